// Round 1
// baseline (198.290 us; speedup 1.0000x reference)
//
#include <hip/hip_runtime.h>

#define N_NODES 2048
#define F_IN    128
#define HD      32
#define E_EDGES 65536
#define P_PAIRS 768

// ---------------- degree / norm ----------------
__global__ void k_deg(const int* __restrict__ dst, int* __restrict__ deg) {
    int e = blockIdx.x * 256 + threadIdx.x;
    if (e < E_EDGES) atomicAdd(&deg[dst[e]], 1);
}

__global__ void k_dinv(const int* __restrict__ deg, float* __restrict__ dinv) {
    int n = blockIdx.x * 256 + threadIdx.x;
    if (n < N_NODES) dinv[n] = 1.0f / sqrtf((float)(deg[n] + 1)); // +1 self loop
}

// ---------------- dense matmul (N x K) @ (K x 32) ----------------
template <int K>
__global__ void k_matmul(const float* __restrict__ in, const float* __restrict__ W,
                         float* __restrict__ out) {
    int t = blockIdx.x * 256 + threadIdx.x;
    int n = t >> 5, j = t & 31;
    if (n >= N_NODES) return;
    const float* row = in + n * K;
    float acc = 0.f;
#pragma unroll 8
    for (int k = 0; k < K; ++k) acc = fmaf(row[k], W[k * HD + j], acc);
    out[n * HD + j] = acc;
}

// ---------------- edge scatter: acc[d] += hW[s]*dinv[s]*dinv[d] ----------------
__global__ void k_scatter(const int* __restrict__ src, const int* __restrict__ dst,
                          const float* __restrict__ hW, const float* __restrict__ dinv,
                          float* __restrict__ acc) {
    int t = blockIdx.x * 256 + threadIdx.x; // E*32 threads
    int e = t >> 5, h = t & 31;
    if (e >= E_EDGES) return;
    int s = src[e], d = dst[e];
    float w = dinv[s] * dinv[d];
    atomicAdd(&acc[d * HD + h], hW[s * HD + h] * w);
}

// ---------------- self loop + bias ----------------
__global__ void k_finish(const float* __restrict__ hW, const float* __restrict__ dinv,
                         const float* __restrict__ b, float* __restrict__ acc) {
    int t = blockIdx.x * 256 + threadIdx.x;
    int n = t >> 5, h = t & 31;
    if (n >= N_NODES) return;
    float di = dinv[n];
    acc[n * HD + h] += hW[n * HD + h] * di * di + b[h];
}

// ---------------- per-edge: xe -> two (32x32 matmul + LN + relu), eid scatter ----
__global__ void k_edge_mlp(const int* __restrict__ src, const int* __restrict__ dst,
                           const float* __restrict__ h2,
                           const float* __restrict__ m1w, const float* __restrict__ m1b,
                           const float* __restrict__ m1g, const float* __restrict__ m1be,
                           const float* __restrict__ m2w, const float* __restrict__ m2b,
                           const float* __restrict__ m2g, const float* __restrict__ m2be,
                           float* __restrict__ x1, float* __restrict__ x2,
                           int* __restrict__ eid) {
    __shared__ float s_w1[HD * HD], s_w2[HD * HD];
    int tid = threadIdx.x; // 256 = 8 edges x 32 lanes
    for (int i = tid; i < HD * HD; i += 256) { s_w1[i] = m1w[i]; s_w2[i] = m2w[i]; }
    __syncthreads();
    int e = blockIdx.x * 8 + (tid >> 5);
    int j = tid & 31;
    int s = src[e], d = dst[e];
    float xe = h2[s * HD + j] * h2[d * HD + j];
    float y1 = m1b[j], y2 = m2b[j];
#pragma unroll
    for (int k = 0; k < HD; ++k) {
        float xk = __shfl(xe, k, 32);
        y1 = fmaf(xk, s_w1[k * HD + j], y1);
        y2 = fmaf(xk, s_w2[k * HD + j], y2);
    }
    // LayerNorm over 32 lanes (two-pass for accuracy)
    float mu1 = y1, mu2 = y2;
#pragma unroll
    for (int m = 16; m > 0; m >>= 1) { mu1 += __shfl_xor(mu1, m, 32); mu2 += __shfl_xor(mu2, m, 32); }
    mu1 *= (1.f / 32.f); mu2 *= (1.f / 32.f);
    float d1 = y1 - mu1, d2 = y2 - mu2;
    float v1 = d1 * d1, v2 = d2 * d2;
#pragma unroll
    for (int m = 16; m > 0; m >>= 1) { v1 += __shfl_xor(v1, m, 32); v2 += __shfl_xor(v2, m, 32); }
    v1 *= (1.f / 32.f); v2 *= (1.f / 32.f);
    float r1 = d1 / sqrtf(v1 + 1e-5f) * m1g[j] + m1be[j];
    float r2 = d2 / sqrtf(v2 + 1e-5f) * m2g[j] + m2be[j];
    x1[e * HD + j] = fmaxf(r1, 0.f);
    x2[e * HD + j] = fmaxf(r2, 0.f);
    // last-writer-wins scatter => max edge index wins
    if (j == 0) atomicMax(&eid[s * N_NODES + d], e);
}

// ---------------- per-pair: 2-hop walk + final MLP ----------------
__global__ void k_pos(const int* __restrict__ pos, const int* __restrict__ eid,
                      const float* __restrict__ x1, const float* __restrict__ x2,
                      const float* __restrict__ h2,
                      const float* __restrict__ w1, const float* __restrict__ b1,
                      const float* __restrict__ w2, const float* __restrict__ b2,
                      float* __restrict__ out) {
    __shared__ float acc[HD];
    __shared__ float sz[2 * HD];
    int p = blockIdx.x;
    int i = pos[p], j = pos[P_PAIRS + p];
    int tid = threadIdx.x;
    if (tid < HD) acc[tid] = 0.f;
    __syncthreads();
    for (int n = tid; n < N_NODES; n += 256) {
        int e1 = eid[i * N_NODES + n];
        if (e1 < 0) continue;
        int e2 = eid[n * N_NODES + j];
        if (e2 < 0) continue;
#pragma unroll
        for (int h = 0; h < HD; ++h)
            atomicAdd(&acc[h], x2[e1 * HD + h] * x1[e2 * HD + h]);
    }
    __syncthreads();
    if (tid < HD) {
        sz[tid] = acc[tid];
        sz[HD + tid] = h2[i * HD + tid] * h2[j * HD + tid];
    }
    __syncthreads();
    float r = 0.f;
    if (tid < HD) {
        float t = b1[tid];
#pragma unroll
        for (int k = 0; k < 2 * HD; ++k) t = fmaf(sz[k], w1[k * HD + tid], t);
        t = fmaxf(t, 0.f);
        r = t * w2[tid];
    }
    if (tid < 64) {
#pragma unroll
        for (int m = 16; m > 0; m >>= 1) r += __shfl_xor(r, m, 32);
        if (tid == 0) out[p] = r + b2[0];
    }
}

extern "C" void kernel_launch(void* const* d_in, const int* in_sizes, int n_in,
                              void* d_out, int out_size, void* d_ws, size_t ws_size,
                              hipStream_t stream) {
    const float* x     = (const float*)d_in[0];
    const int*   ei    = (const int*)d_in[1];
    const int*   pos   = (const int*)d_in[2];
    const float* W1    = (const float*)d_in[3];
    const float* b1    = (const float*)d_in[4];
    const float* W2    = (const float*)d_in[5];
    const float* b2    = (const float*)d_in[6];
    const float* m1w   = (const float*)d_in[7];
    const float* m1b   = (const float*)d_in[8];
    const float* m1g   = (const float*)d_in[9];
    const float* m1be  = (const float*)d_in[10];
    const float* m2w   = (const float*)d_in[11];
    const float* m2b   = (const float*)d_in[12];
    const float* m2g   = (const float*)d_in[13];
    const float* m2be  = (const float*)d_in[14];
    const float* m3w1  = (const float*)d_in[15];
    const float* m3b1  = (const float*)d_in[16];
    const float* m3w2  = (const float*)d_in[17];
    const float* m3b2  = (const float*)d_in[18];

    const int* src = ei;
    const int* dst = ei + E_EDGES;

    char* w = (char*)d_ws;
    size_t off = 0;
    auto alloc = [&](size_t bytes) { void* p = w + off; off += (bytes + 255) & ~size_t(255); return p; };
    int*   deg  = (int*)  alloc(N_NODES * 4);
    float* dinv = (float*)alloc(N_NODES * 4);
    float* hW   = (float*)alloc(N_NODES * HD * 4);
    float* h1   = (float*)alloc(N_NODES * HD * 4);
    float* hW2  = (float*)alloc(N_NODES * HD * 4);
    float* h2   = (float*)alloc(N_NODES * HD * 4);
    float* x1   = (float*)alloc((size_t)E_EDGES * HD * 4);
    float* x2   = (float*)alloc((size_t)E_EDGES * HD * 4);
    int*   eid  = (int*)  alloc((size_t)N_NODES * N_NODES * 4);

    hipMemsetAsync(deg, 0, N_NODES * 4, stream);
    hipMemsetAsync(h1, 0, N_NODES * HD * 4, stream);
    hipMemsetAsync(h2, 0, N_NODES * HD * 4, stream);
    hipMemsetAsync(eid, 0xFF, (size_t)N_NODES * N_NODES * 4, stream); // -1

    k_deg<<<E_EDGES / 256, 256, 0, stream>>>(dst, deg);
    k_dinv<<<N_NODES / 256, 256, 0, stream>>>(deg, dinv);

    // layer 1
    k_matmul<F_IN><<<N_NODES * HD / 256, 256, 0, stream>>>(x, W1, hW);
    k_scatter<<<E_EDGES * HD / 256, 256, 0, stream>>>(src, dst, hW, dinv, h1);
    k_finish<<<N_NODES * HD / 256, 256, 0, stream>>>(hW, dinv, b1, h1);
    // layer 2
    k_matmul<HD><<<N_NODES * HD / 256, 256, 0, stream>>>(h1, W2, hW2);
    k_scatter<<<E_EDGES * HD / 256, 256, 0, stream>>>(src, dst, hW2, dinv, h2);
    k_finish<<<N_NODES * HD / 256, 256, 0, stream>>>(hW2, dinv, b2, h2);
    // per-edge MLPs + eid scatter
    k_edge_mlp<<<E_EDGES / 8, 256, 0, stream>>>(src, dst, h2,
        m1w, m1b, m1g, m1be, m2w, m2b, m2g, m2be, x1, x2, eid);
    // per-pair walk + final MLP
    k_pos<<<P_PAIRS, 256, 0, stream>>>(pos, eid, x1, x2, h2, m3w1, m3b1, m3w2, m3b2,
                                       (float*)d_out);
}